// Round 5
// baseline (2788.052 us; speedup 1.0000x reference)
//
#include <hip/hip_runtime.h>
#include <hip/hip_bf16.h>
#include <math.h>

typedef __hip_bfloat16 bf16;
typedef __attribute__((ext_vector_type(8))) short short8;
typedef __attribute__((ext_vector_type(4))) short short4v;
typedef __attribute__((ext_vector_type(4))) float f32x4;

// problem dims
#define B_    64
#define T_    512
#define D_    128
#define N_    510
#define H_    512
#define TOK_  384
#define PRED1_ 12533760L  // B_*N_*TOK_
#define TOKOFF_ 37601280L // 3*PRED1_ : tokens offset in d_out (floats)

// ---- workspace layout (bytes) ----
#define O_XBF  0UL            // x bf16            8,388,608
#define O_SWB  8388608UL      // sess_W bf16         524,288
#define O_PW   8912896UL      // proj_W bf16         393,216
#define O_WIH  9306112UL      // gru_Wih bf16      1,572,864
#define O_WHH  10878976UL     // gru_Whh bf16      1,572,864
#define O_W1   12451840UL     // head_W1 bf16      1,572,864
#define O_W2   14024704UL     // head_W2 bf16      1,179,648
#define O_TOK  15204352UL     // tokens bf16      25,067,520  rows [n*64+b]
#define O_HBF  40271872UL     // h bf16 (post-RMS)33,423,360
#define O_HID  73695232UL     // hidden bf16      33,423,360  rows [s*64+b]
#define O_ABF  107118592UL    // gelu act bf16 (first 32KB doubles as GRU flags)
#define O_GX   140541952UL    // gx bf16 100,270,080 (h_pre fp32 overlapped first)

// ---------------- fp32 -> bf16 convert ----------------
__global__ void k_f2b(const float* __restrict__ s, bf16* __restrict__ d, int n4) {
  int i = blockIdx.x * 256 + threadIdx.x;
  if (i < n4) {
    float4 v = ((const float4*)s)[i];
    union { short4v sv; bf16 h[4]; } u;
    u.h[0] = __float2bfloat16(v.x); u.h[1] = __float2bfloat16(v.y);
    u.h[2] = __float2bfloat16(v.z); u.h[3] = __float2bfloat16(v.w);
    ((short4v*)d)[i] = u.sv;
  }
}

// ---------------- generic bf16 MFMA GEMM: C = A[M,K] @ W[N,K]^T + bias ----------------
enum { EPI_F32 = 0, EPI_BF16 = 1, EPI_GELU = 2, EPI_TOK = 3, EPI_F32R = 4 };
#define SLDA 40

template <int EPI>
__global__ __launch_bounds__(256, 2) void k_gemm(
    const bf16* __restrict__ A, const bf16* __restrict__ W,
    const float* __restrict__ bias, void* __restrict__ C,
    int K, int ldc, long zA, long zW, long zB, long zC,
    const int* __restrict__ sidx, float* __restrict__ tokf, bf16* __restrict__ tokb)
{
  const int tid = threadIdx.x;
  const int bm = blockIdx.x, bn = blockIdx.y, z = blockIdx.z;
  const int wsel = (EPI == EPI_TOK) ? sidx[z] : z;
  const int lane = tid & 63, wave = tid >> 6;
  const int wm = (wave & 1) << 6, wn = (wave >> 1) << 6;
  const int r16 = lane & 15, quad = lane >> 4;

  __shared__ bf16 sA[128 * SLDA];
  __shared__ bf16 sB[128 * SLDA];

  const bf16* Ag = A + (long)z * zA + (long)bm * 128 * K;
  const bf16* Wg = W + (long)wsel * zW + (long)bn * 128 * K;

  f32x4 zf = {0.f, 0.f, 0.f, 0.f};
  f32x4 acc[4][4];
  for (int i = 0; i < 4; ++i) for (int j = 0; j < 4; ++j) acc[i][j] = zf;

  const int sr = tid >> 1, sc = (tid & 1) << 4;
  for (int k0 = 0; k0 < K; k0 += 32) {
    *(short8*)&sA[sr*SLDA + sc]     = *(const short8*)&Ag[(long)sr*K + k0 + sc];
    *(short8*)&sA[sr*SLDA + sc + 8] = *(const short8*)&Ag[(long)sr*K + k0 + sc + 8];
    *(short8*)&sB[sr*SLDA + sc]     = *(const short8*)&Wg[(long)sr*K + k0 + sc];
    *(short8*)&sB[sr*SLDA + sc + 8] = *(const short8*)&Wg[(long)sr*K + k0 + sc + 8];
    __syncthreads();
    short8 fa[4], fb[4];
    for (int i = 0; i < 4; ++i) fa[i] = *(const short8*)&sA[(wm + i*16 + r16)*SLDA + quad*8];
    for (int j = 0; j < 4; ++j) fb[j] = *(const short8*)&sB[(wn + j*16 + r16)*SLDA + quad*8];
    for (int i = 0; i < 4; ++i)
      for (int j = 0; j < 4; ++j)
        acc[i][j] = __builtin_amdgcn_mfma_f32_16x16x32_bf16(fa[i], fb[j], acc[i][j], 0, 0, 0);
    __syncthreads();
  }

  const float* bz = bias + (long)wsel * zB + bn * 128;
  for (int i = 0; i < 4; ++i) {
    for (int j = 0; j < 4; ++j) {
      const int colL = wn + j*16 + r16;
      const float bv = bz[colL];
      for (int r = 0; r < 4; ++r) {
        float v = acc[i][j][r] + bv;
        const long grow = (long)bm*128 + wm + i*16 + quad*4 + r;
        const long gcol = (long)bn*128 + colL;
        if (EPI == EPI_F32) {
          ((float*)C)[(long)z*zC + grow*ldc + gcol] = v;
        } else if (EPI == EPI_BF16) {
          ((bf16*)C)[(long)z*zC + grow*ldc + gcol] = __float2bfloat16(v);
        } else if (EPI == EPI_GELU) {
          v = 0.5f * v * (1.0f + erff(v * 0.70710678118654752f));
          ((bf16*)C)[(long)z*zC + grow*ldc + gcol] = __float2bfloat16(v);
        } else if (EPI == EPI_F32R) {
          // rows are [n*64+b]; output wants [b*510+n]
          const long rb = grow & 63, rn = grow >> 6;
          ((float*)C)[(rb*510 + rn)*ldc + gcol] = v;
        } else { // EPI_TOK: z=batch, grow=t, gcol=e
          for (int p = 0; p < 3; ++p) {
            long n = grow - p;
            if (n >= 0 && n < N_) {
              tokf[((long)z*N_ + n)*TOK_ + gcol*3 + p] = v;                 // d_out: [b][n][tok]
              tokb[((long)n*B_ + z)*TOK_ + gcol*3 + p] = __float2bfloat16(v); // ws: rows [n*64+b]
            }
          }
        }
      }
    }
  }
}

// ---------------- RMSNorm rows of 512: fp32 in -> bf16 out ----------------
__global__ __launch_bounds__(256) void k_rms(const float* __restrict__ hpre,
                                             const float* __restrict__ scale,
                                             bf16* __restrict__ hbf)
{
  const int wave = threadIdx.x >> 6, lane = threadIdx.x & 63;
  const long row = (long)blockIdx.x * 4 + wave;
  const float* p = hpre + row * 512 + lane * 8;
  float4 v0 = *(const float4*)p;
  float4 v1 = *(const float4*)(p + 4);
  float ss = v0.x*v0.x + v0.y*v0.y + v0.z*v0.z + v0.w*v0.w
           + v1.x*v1.x + v1.y*v1.y + v1.z*v1.z + v1.w*v1.w;
  for (int m = 32; m >= 1; m >>= 1) ss += __shfl_xor(ss, m, 64);
  const float inv = 1.0f / sqrtf(ss * (1.0f/512.0f) + 1e-6f);
  const float* sc = scale + lane * 8;
  union { short8 sv; bf16 h[8]; } u;
  u.h[0] = __float2bfloat16(v0.x*inv*sc[0]); u.h[1] = __float2bfloat16(v0.y*inv*sc[1]);
  u.h[2] = __float2bfloat16(v0.z*inv*sc[2]); u.h[3] = __float2bfloat16(v0.w*inv*sc[3]);
  u.h[4] = __float2bfloat16(v1.x*inv*sc[4]); u.h[5] = __float2bfloat16(v1.y*inv*sc[5]);
  u.h[6] = __float2bfloat16(v1.z*inv*sc[6]); u.h[7] = __float2bfloat16(v1.w*inv*sc[7]);
  *(short8*)(hbf + row * 512 + lane * 8) = u.sv;
}

// ---------------- GRU: single-wave phased-dataflow persistent scan ----------------
// 8 independent batch-groups of 8 batches; per group 32 single-wave WGs
// (grid 256 x 64 thr, 1 wave/CU). Wave pw owns cols [16pw,16pw+16), all 3 gates.
// Round-4 lessons applied:
//  * 4-phase IN-ORDER dataflow wait: phase p waits producers 8p..8p+7 only,
//    then loads + MFMAs kts 4p..4p+3. Deterministic kt order 0..15 (bit-identical
//    sums), but load+MFMA work overlaps the producer straggle window; only the
//    last phase + gate tail sits after the final flag. Fast path: one poll
//    covers all phases when every flag is already set.
//  * weight LDS layout [kt][gate][lane*8]: every wave read is 1KB contiguous
//    -> zero bank conflicts (was 2.5e7 conflict cycles with padded rows).
//  * h_prev for the z*h term kept in registers (it is this wave's own output).
__global__ __launch_bounds__(64, 1) void k_gru(
    const bf16* __restrict__ gx,   // [s][b][1536] bf16 (bih already added)
    const bf16* __restrict__ Whh,  // [1536][512] bf16
    const float* __restrict__ bhh, // [1536]
    bf16* __restrict__ hidden,     // [s][b][512] bf16
    int* __restrict__ flags)       // 8 groups x 32 flags, 32 ints apart
{
  const int lane = threadIdx.x & 63;
  const int c16  = lane & 15, quad = lane >> 4;
  const int pw   = blockIdx.x & 31;     // producer-wave id within group
  const int gb   = blockIdx.x >> 5;     // batch group
  const int hwv  = pw * 16;             // column base
  const int b0   = gb * 8;              // batch base

  __shared__ bf16 wlds[16 * 3 * 64 * 8];  // [kt][gate][lane*8] : 49,152 B

  // one-time stage: B-frag for (kt,gate) at this lane = Whh row (g*512+hwv+c16),
  // cols kt*32+quad*8 .. +8  -> stored lane-contiguous (conflict-free)
  for (int g3 = 0; g3 < 3; ++g3)
    for (int kt = 0; kt < 16; ++kt)
      *(short8*)&wlds[((kt*3 + g3)*64 + lane)*8] =
          *(const short8*)&Whh[(long)(g3*512 + hwv + c16)*512 + kt*32 + quad*8];
  const float bhr = bhh[       hwv + c16];
  const float bhz = bhh[ 512 + hwv + c16];
  const float bhn = bhh[1024 + hwv + c16];
  __syncthreads();

  int* myflag = &flags[(gb*32 + pw) * 32];
  const int pidx = (gb*32 + (lane & 31)) * 32;
  // lane owns output batch rows brv..brv+3 (valid for quad<2; quads 2,3 mirror)
  const int brv = (quad & 1) * 4;

  float gr[4], gz[4], gn[4], pr[4], pz[4], pn[4];
  float hcur[4] = {0.f, 0.f, 0.f, 0.f};   // own cols' h (z*h_prev term), in regs
  { // gx for s=0
    const bf16* gxs = gx + (long)b0 * 1536 + hwv + c16;
#pragma unroll
    for (int i2 = 0; i2 < 4; ++i2) {
      const long ro = (long)(brv + i2) * 1536;
      gr[i2] = __bfloat162float(gxs[ro]);
      gz[i2] = __bfloat162float(gxs[ro + 512]);
      gn[i2] = __bfloat162float(gxs[ro + 1024]);
    }
  }

  for (int s = 0; s < 510; ++s) {
    // prefetch gx for s+1 FIRST: HBM latency hides under the phase waits
    {
      const int s1 = (s < 509) ? s + 1 : 509;
      const bf16* gxs = gx + ((long)s1*64 + b0)*1536 + hwv + c16;
#pragma unroll
      for (int i2 = 0; i2 < 4; ++i2) {
        const long ro = (long)(brv + i2) * 1536;
        pr[i2] = __bfloat162float(gxs[ro]);
        pz[i2] = __bfloat162float(gxs[ro + 512]);
        pn[i2] = __bfloat162float(gxs[ro + 1024]);
      }
    }

    f32x4 ar = {0.f,0.f,0.f,0.f}, az = {0.f,0.f,0.f,0.f}, an = {0.f,0.f,0.f,0.f};

    if (s > 0) {
      const unsigned long long* hq = (const unsigned long long*)
          (hidden + ((long)(s-1)*64 + b0 + (c16 & 7)) * 512);
      unsigned blv = 0;   // cached ballot of (flag >= s) across producers 0..31
#pragma unroll
      for (int ph = 0; ph < 4; ++ph) {
        const unsigned pm = 0xFFu << (ph*8);   // producers 8ph..8ph+7
        if ((blv & pm) != pm) {
          while (true) {
            int fv = __hip_atomic_load(&flags[pidx], __ATOMIC_RELAXED, __HIP_MEMORY_SCOPE_AGENT);
            blv = (unsigned)__ballot(fv >= s);
            if ((blv & pm) == pm) break;
            __builtin_amdgcn_s_sleep(1);
          }
          asm volatile("" ::: "memory");  // loads below stay after the poll
        }
        // load this phase's 4 kt-slices (cols [ph*128, ph*128+128) of h_prev)
        union { unsigned long long q[2]; short8 s8; } au4[4];
#pragma unroll
        for (int k4 = 0; k4 < 4; ++k4) {
          const int kt = ph*4 + k4;
          au4[k4].q[0] = __hip_atomic_load(hq + kt*8 + quad*2,     __ATOMIC_RELAXED, __HIP_MEMORY_SCOPE_AGENT);
          au4[k4].q[1] = __hip_atomic_load(hq + kt*8 + quad*2 + 1, __ATOMIC_RELAXED, __HIP_MEMORY_SCOPE_AGENT);
        }
#pragma unroll
        for (int k4 = 0; k4 < 4; ++k4) {
          const int kt = ph*4 + k4;
          short8 fr = *(const short8*)&wlds[((kt*3 + 0)*64 + lane)*8];
          short8 fz = *(const short8*)&wlds[((kt*3 + 1)*64 + lane)*8];
          short8 fn = *(const short8*)&wlds[((kt*3 + 2)*64 + lane)*8];
          ar = __builtin_amdgcn_mfma_f32_16x16x32_bf16(au4[k4].s8, fr, ar, 0, 0, 0);
          az = __builtin_amdgcn_mfma_f32_16x16x32_bf16(au4[k4].s8, fz, az, 0, 0, 0);
          an = __builtin_amdgcn_mfma_f32_16x16x32_bf16(au4[k4].s8, fn, an, 0, 0, 0);
        }
      }
    }

    // gates + publish (only quad<2 lanes own valid batch rows)
    if (quad < 2) {
#pragma unroll
      for (int i2 = 0; i2 < 4; ++i2) {
        const float r  = 1.0f / (1.0f + expf(-(gr[i2] + ar[i2] + bhr)));
        const float z  = 1.0f / (1.0f + expf(-(gz[i2] + az[i2] + bhz)));
        const float nn = tanhf(gn[i2] + r * (an[i2] + bhn));
        const float hn = (1.0f - z)*nn + z*hcur[i2];
        union { bf16 h; unsigned short u; } cb; cb.h = __float2bfloat16(hn);
        hcur[i2] = __bfloat162float(cb.h);     // exact stored value for next step
        unsigned mine = cb.u;
        unsigned part = (unsigned)__shfl_xor((int)mine, 1, 64);
        if (!(c16 & 1)) {
          unsigned w = (part << 16) | mine;    // lo = col c16, hi = col c16+1
          __hip_atomic_store((unsigned*)(hidden + ((long)s*64 + b0 + brv + i2)*512 + hwv + c16),
                             w, __ATOMIC_RELAXED, __HIP_MEMORY_SCOPE_AGENT);
        }
      }
    }
    if (s < 509) {  // last step has no consumer; stores drain at kernel end
      asm volatile("s_waitcnt vmcnt(0)" ::: "memory");  // data acked, then flag
      if (lane == 0)
        __hip_atomic_store(myflag, s + 1, __ATOMIC_RELAXED, __HIP_MEMORY_SCOPE_AGENT);
    }
#pragma unroll
    for (int i2 = 0; i2 < 4; ++i2) { gr[i2]=pr[i2]; gz[i2]=pz[i2]; gn[i2]=pn[i2]; }
  }
}

// ---------------- launch ----------------
extern "C" void kernel_launch(void* const* d_in, const int* in_sizes, int n_in,
                              void* d_out, int out_size, void* d_ws, size_t ws_size,
                              hipStream_t stream)
{
  const float* x    = (const float*)d_in[0];
  const int*   sidx = (const int*)d_in[1];
  const float* sW   = (const float*)d_in[2];
  const float* sb   = (const float*)d_in[3];
  const float* pW   = (const float*)d_in[4];
  const float* pb   = (const float*)d_in[5];
  const float* rsc  = (const float*)d_in[6];
  const float* wih  = (const float*)d_in[7];
  const float* whh  = (const float*)d_in[8];
  const float* bih  = (const float*)d_in[9];
  const float* bhh  = (const float*)d_in[10];
  const float* w1   = (const float*)d_in[11];
  const float* b1   = (const float*)d_in[12];
  const float* w2   = (const float*)d_in[13];
  const float* b2   = (const float*)d_in[14];
  char* ws = (char*)d_ws;
  float* out = (float*)d_out;

  bf16* xbf   = (bf16*)(ws + O_XBF);
  bf16* swbf  = (bf16*)(ws + O_SWB);
  bf16* pwbf  = (bf16*)(ws + O_PW);
  bf16* wihbf = (bf16*)(ws + O_WIH);
  bf16* whhbf = (bf16*)(ws + O_WHH);
  bf16* w1bf  = (bf16*)(ws + O_W1);
  bf16* w2bf  = (bf16*)(ws + O_W2);
  bf16* tokbf = (bf16*)(ws + O_TOK);
  bf16* hbf   = (bf16*)(ws + O_HBF);
  bf16* hidbf = (bf16*)(ws + O_HID);
  bf16* abf   = (bf16*)(ws + O_ABF);
  int*  bar   = (int*)(ws + O_ABF);   // flags live in abf (dead during GRU)
  float* hpre = (float*)(ws + O_GX);  // fp32 h_pre overlaps gx region
  bf16* gxbf  = (bf16*)(ws + O_GX);

  auto cvt = [&](const float* s, bf16* dp, long n) {
    int n4 = (int)(n >> 2);
    k_f2b<<<dim3((n4 + 255) / 256), dim3(256), 0, stream>>>(s, dp, n4);
  };
  cvt(x,   xbf,   (long)B_*T_*D_);
  cvt(sW,  swbf,  16L*128*128);
  cvt(pW,  pwbf,  512L*384);
  cvt(wih, wihbf, 1536L*512);
  cvt(whh, whhbf, 1536L*512);
  cvt(w1,  w1bf,  3L*512*512);
  cvt(w2,  w2bf,  3L*384*512);

  // 1) session align -> tokens (fp32 to d_out [b][n][tok], bf16 to ws rows [n*64+b])
  k_gemm<EPI_TOK><<<dim3(4, 1, 64), dim3(256), 0, stream>>>(
      xbf, swbf, sb, nullptr, 128, 0,
      (long)T_*D_, 128L*128, 128L, 0L, sidx, out + TOKOFF_, tokbf);

  // 2) proj: h_pre = tokens @ proj_W^T + b  (fp32, rows [n*64+b])
  k_gemm<EPI_F32><<<dim3(255, 4, 1), dim3(256), 0, stream>>>(
      tokbf, pwbf, pb, hpre, 384, 512, 0, 0, 0, 0, nullptr, nullptr, nullptr);

  // 3) RMSNorm -> h bf16
  k_rms<<<dim3(8160), dim3(256), 0, stream>>>(hpre, rsc, hbf);

  // 4) gx = h @ Wih^T + bih  (bf16, rows [n*64+b] == [s][b][1536])
  k_gemm<EPI_BF16><<<dim3(255, 12, 1), dim3(256), 0, stream>>>(
      hbf, wihbf, bih, gxbf, 512, 1536, 0, 0, 0, 0, nullptr, nullptr, nullptr);

  // 5) GRU scan: 8 groups x 32 single-wave WGs = 256 WGs x 64 thr (1 wave/CU).
  //    Flags: 8*32 x 128B = 32KB, zeroed first (abf region is dead until heads).
  hipMemsetAsync(ws + O_ABF, 0, 32768, stream);
  k_gru<<<dim3(256), dim3(64), 0, stream>>>(gxbf, whhbf, bhh, hidbf, bar);

  // 6) heads: a = gelu(hidden @ W1^T + b1); preds = a @ W2^T + b2 (remap rows)
  for (int k = 0; k < 3; ++k) {
    k_gemm<EPI_GELU><<<dim3(255, 4, 1), dim3(256), 0, stream>>>(
        hidbf, w1bf + (long)k*512*512, b1 + (long)k*512, abf,
        512, 512, 0, 0, 0, 0, nullptr, nullptr, nullptr);
    k_gemm<EPI_F32R><<<dim3(255, 3, 1), dim3(256), 0, stream>>>(
        abf, w2bf + (long)k*384*512, b2 + (long)k*384, out + (long)k*PRED1_,
        512, 384, 0, 0, 0, 0, nullptr, nullptr, nullptr);
  }
}

// Round 6
// 2385.105 us; speedup vs baseline: 1.1689x; 1.1689x over previous
//
#include <hip/hip_runtime.h>
#include <hip/hip_bf16.h>
#include <math.h>

typedef __hip_bfloat16 bf16;
typedef __attribute__((ext_vector_type(8))) short short8;
typedef __attribute__((ext_vector_type(4))) short short4v;
typedef __attribute__((ext_vector_type(4))) float f32x4;

// problem dims
#define B_    64
#define T_    512
#define D_    128
#define N_    510
#define H_    512
#define TOK_  384
#define PRED1_ 12533760L  // B_*N_*TOK_
#define TOKOFF_ 37601280L // 3*PRED1_ : tokens offset in d_out (floats)

// ---- workspace layout (bytes) ----
#define O_XBF  0UL            // x bf16            8,388,608
#define O_SWB  8388608UL      // sess_W bf16         524,288
#define O_PW   8912896UL      // proj_W bf16         393,216
#define O_WIH  9306112UL      // gru_Wih bf16      1,572,864
#define O_WHH  10878976UL     // gru_Whh bf16      1,572,864
#define O_W1   12451840UL     // head_W1 bf16      1,572,864
#define O_W2   14024704UL     // head_W2 bf16      1,179,648
#define O_TOK  15204352UL     // tokens bf16      25,067,520  rows [n*64+b]
#define O_HBF  40271872UL     // h bf16 (post-RMS)33,423,360
#define O_HID  73695232UL     // hidden bf16      33,423,360  rows [s*64+b]
#define O_ABF  107118592UL    // gelu act bf16 (first 32KB doubles as GRU flags)
#define O_GX   140541952UL    // gx bf16 100,270,080 (h_pre fp32 overlapped first)

// ---------------- fp32 -> bf16 convert ----------------
__global__ void k_f2b(const float* __restrict__ s, bf16* __restrict__ d, int n4) {
  int i = blockIdx.x * 256 + threadIdx.x;
  if (i < n4) {
    float4 v = ((const float4*)s)[i];
    union { short4v sv; bf16 h[4]; } u;
    u.h[0] = __float2bfloat16(v.x); u.h[1] = __float2bfloat16(v.y);
    u.h[2] = __float2bfloat16(v.z); u.h[3] = __float2bfloat16(v.w);
    ((short4v*)d)[i] = u.sv;
  }
}

// ---------------- generic bf16 MFMA GEMM: C = A[M,K] @ W[N,K]^T + bias ----------------
enum { EPI_F32 = 0, EPI_BF16 = 1, EPI_GELU = 2, EPI_TOK = 3, EPI_F32R = 4 };
#define SLDA 40

template <int EPI>
__global__ __launch_bounds__(256, 2) void k_gemm(
    const bf16* __restrict__ A, const bf16* __restrict__ W,
    const float* __restrict__ bias, void* __restrict__ C,
    int K, int ldc, long zA, long zW, long zB, long zC,
    const int* __restrict__ sidx, float* __restrict__ tokf, bf16* __restrict__ tokb)
{
  const int tid = threadIdx.x;
  const int bm = blockIdx.x, bn = blockIdx.y, z = blockIdx.z;
  const int wsel = (EPI == EPI_TOK) ? sidx[z] : z;
  const int lane = tid & 63, wave = tid >> 6;
  const int wm = (wave & 1) << 6, wn = (wave >> 1) << 6;
  const int r16 = lane & 15, quad = lane >> 4;

  __shared__ bf16 sA[128 * SLDA];
  __shared__ bf16 sB[128 * SLDA];

  const bf16* Ag = A + (long)z * zA + (long)bm * 128 * K;
  const bf16* Wg = W + (long)wsel * zW + (long)bn * 128 * K;

  f32x4 zf = {0.f, 0.f, 0.f, 0.f};
  f32x4 acc[4][4];
  for (int i = 0; i < 4; ++i) for (int j = 0; j < 4; ++j) acc[i][j] = zf;

  const int sr = tid >> 1, sc = (tid & 1) << 4;
  for (int k0 = 0; k0 < K; k0 += 32) {
    *(short8*)&sA[sr*SLDA + sc]     = *(const short8*)&Ag[(long)sr*K + k0 + sc];
    *(short8*)&sA[sr*SLDA + sc + 8] = *(const short8*)&Ag[(long)sr*K + k0 + sc + 8];
    *(short8*)&sB[sr*SLDA + sc]     = *(const short8*)&Wg[(long)sr*K + k0 + sc];
    *(short8*)&sB[sr*SLDA + sc + 8] = *(const short8*)&Wg[(long)sr*K + k0 + sc + 8];
    __syncthreads();
    short8 fa[4], fb[4];
    for (int i = 0; i < 4; ++i) fa[i] = *(const short8*)&sA[(wm + i*16 + r16)*SLDA + quad*8];
    for (int j = 0; j < 4; ++j) fb[j] = *(const short8*)&sB[(wn + j*16 + r16)*SLDA + quad*8];
    for (int i = 0; i < 4; ++i)
      for (int j = 0; j < 4; ++j)
        acc[i][j] = __builtin_amdgcn_mfma_f32_16x16x32_bf16(fa[i], fb[j], acc[i][j], 0, 0, 0);
    __syncthreads();
  }

  const float* bz = bias + (long)wsel * zB + bn * 128;
  for (int i = 0; i < 4; ++i) {
    for (int j = 0; j < 4; ++j) {
      const int colL = wn + j*16 + r16;
      const float bv = bz[colL];
      for (int r = 0; r < 4; ++r) {
        float v = acc[i][j][r] + bv;
        const long grow = (long)bm*128 + wm + i*16 + quad*4 + r;
        const long gcol = (long)bn*128 + colL;
        if (EPI == EPI_F32) {
          ((float*)C)[(long)z*zC + grow*ldc + gcol] = v;
        } else if (EPI == EPI_BF16) {
          ((bf16*)C)[(long)z*zC + grow*ldc + gcol] = __float2bfloat16(v);
        } else if (EPI == EPI_GELU) {
          v = 0.5f * v * (1.0f + erff(v * 0.70710678118654752f));
          ((bf16*)C)[(long)z*zC + grow*ldc + gcol] = __float2bfloat16(v);
        } else if (EPI == EPI_F32R) {
          // rows are [n*64+b]; output wants [b*510+n]
          const long rb = grow & 63, rn = grow >> 6;
          ((float*)C)[(rb*510 + rn)*ldc + gcol] = v;
        } else { // EPI_TOK: z=batch, grow=t, gcol=e
          for (int p = 0; p < 3; ++p) {
            long n = grow - p;
            if (n >= 0 && n < N_) {
              tokf[((long)z*N_ + n)*TOK_ + gcol*3 + p] = v;                 // d_out: [b][n][tok]
              tokb[((long)n*B_ + z)*TOK_ + gcol*3 + p] = __float2bfloat16(v); // ws: rows [n*64+b]
            }
          }
        }
      }
    }
  }
}

// ---------------- RMSNorm rows of 512: fp32 in -> bf16 out ----------------
__global__ __launch_bounds__(256) void k_rms(const float* __restrict__ hpre,
                                             const float* __restrict__ scale,
                                             bf16* __restrict__ hbf)
{
  const int wave = threadIdx.x >> 6, lane = threadIdx.x & 63;
  const long row = (long)blockIdx.x * 4 + wave;
  const float* p = hpre + row * 512 + lane * 8;
  float4 v0 = *(const float4*)p;
  float4 v1 = *(const float4*)(p + 4);
  float ss = v0.x*v0.x + v0.y*v0.y + v0.z*v0.z + v0.w*v0.w
           + v1.x*v1.x + v1.y*v1.y + v1.z*v1.z + v1.w*v1.w;
  for (int m = 32; m >= 1; m >>= 1) ss += __shfl_xor(ss, m, 64);
  const float inv = 1.0f / sqrtf(ss * (1.0f/512.0f) + 1e-6f);
  const float* sc = scale + lane * 8;
  union { short8 sv; bf16 h[8]; } u;
  u.h[0] = __float2bfloat16(v0.x*inv*sc[0]); u.h[1] = __float2bfloat16(v0.y*inv*sc[1]);
  u.h[2] = __float2bfloat16(v0.z*inv*sc[2]); u.h[3] = __float2bfloat16(v0.w*inv*sc[3]);
  u.h[4] = __float2bfloat16(v1.x*inv*sc[4]); u.h[5] = __float2bfloat16(v1.y*inv*sc[5]);
  u.h[6] = __float2bfloat16(v1.z*inv*sc[6]); u.h[7] = __float2bfloat16(v1.w*inv*sc[7]);
  *(short8*)(hbf + row * 512 + lane * 8) = u.sv;
}

// ---------------- GRU: single-wave persistent scan, DMA-staged h_prev ----------------
// 8 independent batch-groups of 8 batches; per group 32 single-wave WGs
// (grid 256 x 64 thr, 1 wave/CU). Wave pw owns cols [16pw,16pw+16), all 3 gates.
// Per-round lessons fused:
//  r2: h_prev staged via global_load_lds DMA (8 coalesced 1KB bursts, sc1) --
//      the scattered per-lane agent atomic loads of r4/r5 were the dominant
//      exposed latency (~9.7k cy/step stall at VALUBusy 5%).
//  r4: one wave computes all three gates (no barriers, no LDS gate exchange).
//  r5: weights in LDS, layout [kt][gate][lane*8] -> conflict-free; single
//      unphased poll (phasing serializes load latency); hcur in registers.
//  new: gx prefetch AFTER the flag store (off the producer critical edge;
//      HBM latency hides under the next step's poll).
#define KP 520   // LDS row pad (elems): rows land on distinct bank groups

// aux=16 == CPol SC1 on gfx950: device-scope load (coherent past L2)
#define GL2LDS(g, l) __builtin_amdgcn_global_load_lds( \
    (const __attribute__((address_space(1))) void*)(g), \
    (__attribute__((address_space(3))) void*)(l), 16, 0, 16)

__global__ __launch_bounds__(64, 1) void k_gru(
    const bf16* __restrict__ gx,   // [s][b][1536] bf16 (bih already added)
    const bf16* __restrict__ Whh,  // [1536][512] bf16
    const float* __restrict__ bhh, // [1536]
    bf16* __restrict__ hidden,     // [s][b][512] bf16
    int* __restrict__ flags)       // 8 groups x 32 flags, 32 ints apart
{
  const int lane = threadIdx.x & 63;
  const int c16  = lane & 15, quad = lane >> 4;
  const int pw   = blockIdx.x & 31;     // producer-wave id within group
  const int gb   = blockIdx.x >> 5;     // batch group
  const int hwv  = pw * 16;             // column base
  const int b0   = gb * 8;              // batch base

  __shared__ bf16 wlds[16 * 3 * 64 * 8];  // [kt][gate][lane*8] : 49,152 B
  __shared__ bf16 hp[8 * KP];             // h_prev rows (DMA dest): 8,320 B

  // one-time stage: B-frag for (kt,gate) at this lane = Whh row (g*512+hwv+c16),
  // cols kt*32+quad*8 .. +8  -> stored lane-contiguous (conflict-free)
  for (int g3 = 0; g3 < 3; ++g3)
    for (int kt = 0; kt < 16; ++kt)
      *(short8*)&wlds[((kt*3 + g3)*64 + lane)*8] =
          *(const short8*)&Whh[(long)(g3*512 + hwv + c16)*512 + kt*32 + quad*8];
  const float bhr = bhh[       hwv + c16];
  const float bhz = bhh[ 512 + hwv + c16];
  const float bhn = bhh[1024 + hwv + c16];
  __syncthreads();

  int* myflag = &flags[(gb*32 + pw) * 32];
  const int pidx = (gb*32 + (lane & 31)) * 32;
  // lane owns output batch rows brv..brv+3 (valid for quad<2; quads 2,3 mirror)
  const int brv = (quad & 1) * 4;

  float gr[4], gz[4], gn[4];
  float hcur[4] = {0.f, 0.f, 0.f, 0.f};   // own cols' h (z*h_prev term), in regs
  { // gx for s=0
    const bf16* gxs = gx + (long)b0 * 1536 + hwv + c16;
#pragma unroll
    for (int i2 = 0; i2 < 4; ++i2) {
      const long ro = (long)(brv + i2) * 1536;
      gr[i2] = __bfloat162float(gxs[ro]);
      gz[i2] = __bfloat162float(gxs[ro + 512]);
      gn[i2] = __bfloat162float(gxs[ro + 1024]);
    }
  }

  for (int s = 0; s < 510; ++s) {
    f32x4 ar = {0.f,0.f,0.f,0.f}, az = {0.f,0.f,0.f,0.f}, an = {0.f,0.f,0.f,0.f};

    if (s > 0) {
      // single poll over all 32 producers of this group (unphased -- r5 lesson)
      while (true) {
        int fv = __hip_atomic_load(&flags[pidx], __ATOMIC_RELAXED, __HIP_MEMORY_SCOPE_AGENT);
        if (__all(fv >= s)) break;
        __builtin_amdgcn_s_sleep(1);
      }
      asm volatile("" ::: "memory");  // staging stays after the poll

      // stage hidden[s-1] rows b0..b0+7 -> hp: 8 coalesced 1KB DMA bursts (sc1)
      const bf16* src = hidden + ((long)(s-1)*64 + b0)*512 + lane*8;
#pragma unroll
      for (int b = 0; b < 8; ++b) GL2LDS(src + b*512, &hp[b*KP]);
      asm volatile("s_waitcnt vmcnt(0)" ::: "memory");  // DMA landed in hp

      // 48 MFMAs, 3 independent chains; A-frags from hp, B-frags from wlds
#pragma unroll
      for (int kt = 0; kt < 16; ++kt) {
        short8 a  = *(const short8*)&hp[(c16 & 7)*KP + kt*32 + quad*8];
        short8 fr = *(const short8*)&wlds[((kt*3 + 0)*64 + lane)*8];
        short8 fz = *(const short8*)&wlds[((kt*3 + 1)*64 + lane)*8];
        short8 fn = *(const short8*)&wlds[((kt*3 + 2)*64 + lane)*8];
        ar = __builtin_amdgcn_mfma_f32_16x16x32_bf16(a, fr, ar, 0, 0, 0);
        az = __builtin_amdgcn_mfma_f32_16x16x32_bf16(a, fz, az, 0, 0, 0);
        an = __builtin_amdgcn_mfma_f32_16x16x32_bf16(a, fn, an, 0, 0, 0);
      }
    }

    // gates + publish (only quad<2 lanes own valid batch rows)
    if (quad < 2) {
#pragma unroll
      for (int i2 = 0; i2 < 4; ++i2) {
        const float r  = 1.0f / (1.0f + expf(-(gr[i2] + ar[i2] + bhr)));
        const float z  = 1.0f / (1.0f + expf(-(gz[i2] + az[i2] + bhz)));
        const float nn = tanhf(gn[i2] + r * (an[i2] + bhn));
        const float hn = (1.0f - z)*nn + z*hcur[i2];
        union { bf16 h; unsigned short u; } cb; cb.h = __float2bfloat16(hn);
        hcur[i2] = __bfloat162float(cb.h);     // exact stored value for next step
        unsigned mine = cb.u;
        unsigned part = (unsigned)__shfl_xor((int)mine, 1, 64);
        if (!(c16 & 1)) {
          unsigned w = (part << 16) | mine;    // lo = col c16, hi = col c16+1
          __hip_atomic_store((unsigned*)(hidden + ((long)s*64 + b0 + brv + i2)*512 + hwv + c16),
                             w, __ATOMIC_RELAXED, __HIP_MEMORY_SCOPE_AGENT);
        }
      }
    }
    if (s < 509) {  // last step has no consumer; stores drain at kernel end
      asm volatile("s_waitcnt vmcnt(0)" ::: "memory");  // data acked, then flag
      if (lane == 0)
        __hip_atomic_store(myflag, s + 1, __ATOMIC_RELAXED, __HIP_MEMORY_SCOPE_AGENT);
      asm volatile("" ::: "memory");  // keep gx prefetch BELOW the flag store
      // prefetch gx for s+1 -- off critical path, hides under next poll
      const bf16* gxs = gx + ((long)(s+1)*64 + b0)*1536 + hwv + c16;
#pragma unroll
      for (int i2 = 0; i2 < 4; ++i2) {
        const long ro = (long)(brv + i2) * 1536;
        gr[i2] = __bfloat162float(gxs[ro]);
        gz[i2] = __bfloat162float(gxs[ro + 512]);
        gn[i2] = __bfloat162float(gxs[ro + 1024]);
      }
    }
  }
}

// ---------------- launch ----------------
extern "C" void kernel_launch(void* const* d_in, const int* in_sizes, int n_in,
                              void* d_out, int out_size, void* d_ws, size_t ws_size,
                              hipStream_t stream)
{
  const float* x    = (const float*)d_in[0];
  const int*   sidx = (const int*)d_in[1];
  const float* sW   = (const float*)d_in[2];
  const float* sb   = (const float*)d_in[3];
  const float* pW   = (const float*)d_in[4];
  const float* pb   = (const float*)d_in[5];
  const float* rsc  = (const float*)d_in[6];
  const float* wih  = (const float*)d_in[7];
  const float* whh  = (const float*)d_in[8];
  const float* bih  = (const float*)d_in[9];
  const float* bhh  = (const float*)d_in[10];
  const float* w1   = (const float*)d_in[11];
  const float* b1   = (const float*)d_in[12];
  const float* w2   = (const float*)d_in[13];
  const float* b2   = (const float*)d_in[14];
  char* ws = (char*)d_ws;
  float* out = (float*)d_out;

  bf16* xbf   = (bf16*)(ws + O_XBF);
  bf16* swbf  = (bf16*)(ws + O_SWB);
  bf16* pwbf  = (bf16*)(ws + O_PW);
  bf16* wihbf = (bf16*)(ws + O_WIH);
  bf16* whhbf = (bf16*)(ws + O_WHH);
  bf16* w1bf  = (bf16*)(ws + O_W1);
  bf16* w2bf  = (bf16*)(ws + O_W2);
  bf16* tokbf = (bf16*)(ws + O_TOK);
  bf16* hbf   = (bf16*)(ws + O_HBF);
  bf16* hidbf = (bf16*)(ws + O_HID);
  bf16* abf   = (bf16*)(ws + O_ABF);
  int*  bar   = (int*)(ws + O_ABF);   // flags live in abf (dead during GRU)
  float* hpre = (float*)(ws + O_GX);  // fp32 h_pre overlaps gx region
  bf16* gxbf  = (bf16*)(ws + O_GX);

  auto cvt = [&](const float* s, bf16* dp, long n) {
    int n4 = (int)(n >> 2);
    k_f2b<<<dim3((n4 + 255) / 256), dim3(256), 0, stream>>>(s, dp, n4);
  };
  cvt(x,   xbf,   (long)B_*T_*D_);
  cvt(sW,  swbf,  16L*128*128);
  cvt(pW,  pwbf,  512L*384);
  cvt(wih, wihbf, 1536L*512);
  cvt(whh, whhbf, 1536L*512);
  cvt(w1,  w1bf,  3L*512*512);
  cvt(w2,  w2bf,  3L*384*512);

  // 1) session align -> tokens (fp32 to d_out [b][n][tok], bf16 to ws rows [n*64+b])
  k_gemm<EPI_TOK><<<dim3(4, 1, 64), dim3(256), 0, stream>>>(
      xbf, swbf, sb, nullptr, 128, 0,
      (long)T_*D_, 128L*128, 128L, 0L, sidx, out + TOKOFF_, tokbf);

  // 2) proj: h_pre = tokens @ proj_W^T + b  (fp32, rows [n*64+b])
  k_gemm<EPI_F32><<<dim3(255, 4, 1), dim3(256), 0, stream>>>(
      tokbf, pwbf, pb, hpre, 384, 512, 0, 0, 0, 0, nullptr, nullptr, nullptr);

  // 3) RMSNorm -> h bf16
  k_rms<<<dim3(8160), dim3(256), 0, stream>>>(hpre, rsc, hbf);

  // 4) gx = h @ Wih^T + bih  (bf16, rows [n*64+b] == [s][b][1536])
  k_gemm<EPI_BF16><<<dim3(255, 12, 1), dim3(256), 0, stream>>>(
      hbf, wihbf, bih, gxbf, 512, 1536, 0, 0, 0, 0, nullptr, nullptr, nullptr);

  // 5) GRU scan: 8 groups x 32 single-wave WGs = 256 WGs x 64 thr (1 wave/CU).
  //    Flags: 8*32 x 128B = 32KB, zeroed first (abf region is dead until heads).
  hipMemsetAsync(ws + O_ABF, 0, 32768, stream);
  k_gru<<<dim3(256), dim3(64), 0, stream>>>(gxbf, whhbf, bhh, hidbf, bar);

  // 6) heads: a = gelu(hidden @ W1^T + b1); preds = a @ W2^T + b2 (remap rows)
  for (int k = 0; k < 3; ++k) {
    k_gemm<EPI_GELU><<<dim3(255, 4, 1), dim3(256), 0, stream>>>(
        hidbf, w1bf + (long)k*512*512, b1 + (long)k*512, abf,
        512, 512, 0, 0, 0, 0, nullptr, nullptr, nullptr);
    k_gemm<EPI_F32R><<<dim3(255, 3, 1), dim3(256), 0, stream>>>(
        abf, w2bf + (long)k*384*512, b2 + (long)k*384, out + (long)k*PRED1_,
        512, 384, 0, 0, 0, 0, nullptr, nullptr, nullptr);
  }
}

// Round 7
// 2115.493 us; speedup vs baseline: 1.3179x; 1.1274x over previous
//
#include <hip/hip_runtime.h>
#include <hip/hip_bf16.h>
#include <math.h>

typedef __hip_bfloat16 bf16;
typedef __attribute__((ext_vector_type(8))) short short8;
typedef __attribute__((ext_vector_type(4))) short short4v;
typedef __attribute__((ext_vector_type(4))) float f32x4;

// problem dims
#define B_    64
#define T_    512
#define D_    128
#define N_    510
#define H_    512
#define TOK_  384
#define PRED1_ 12533760L  // B_*N_*TOK_
#define TOKOFF_ 37601280L // 3*PRED1_ : tokens offset in d_out (floats)

// ---- workspace layout (bytes) ----
#define O_XBF  0UL            // x bf16            8,388,608
#define O_SWB  8388608UL      // sess_W bf16         524,288
#define O_PW   8912896UL      // proj_W bf16         393,216
#define O_WIH  9306112UL      // gru_Wih bf16      1,572,864
#define O_WHH  10878976UL     // gru_Whh bf16      1,572,864
#define O_W1   12451840UL     // head_W1 bf16      1,572,864
#define O_W2   14024704UL     // head_W2 bf16      1,179,648
#define O_TOK  15204352UL     // tokens bf16      25,067,520  rows [n*64+b]
#define O_HBF  40271872UL     // h bf16 (post-RMS)33,423,360
#define O_HID  73695232UL     // hidden bf16      33,423,360  rows [s*64+b]
#define O_ABF  107118592UL    // gelu act bf16
#define O_GX   140541952UL    // gx bf16 100,270,080 (h_pre fp32 overlapped first)

#define HID_BYTES 33423360UL

// ---------------- fp32 -> bf16 convert ----------------
__global__ void k_f2b(const float* __restrict__ s, bf16* __restrict__ d, int n4) {
  int i = blockIdx.x * 256 + threadIdx.x;
  if (i < n4) {
    float4 v = ((const float4*)s)[i];
    union { short4v sv; bf16 h[4]; } u;
    u.h[0] = __float2bfloat16(v.x); u.h[1] = __float2bfloat16(v.y);
    u.h[2] = __float2bfloat16(v.z); u.h[3] = __float2bfloat16(v.w);
    ((short4v*)d)[i] = u.sv;
  }
}

// ---------------- generic bf16 MFMA GEMM: C = A[M,K] @ W[N,K]^T + bias ----------------
enum { EPI_F32 = 0, EPI_BF16 = 1, EPI_GELU = 2, EPI_TOK = 3, EPI_F32R = 4 };
#define SLDA 40

template <int EPI>
__global__ __launch_bounds__(256, 2) void k_gemm(
    const bf16* __restrict__ A, const bf16* __restrict__ W,
    const float* __restrict__ bias, void* __restrict__ C,
    int K, int ldc, long zA, long zW, long zB, long zC,
    const int* __restrict__ sidx, float* __restrict__ tokf, bf16* __restrict__ tokb)
{
  const int tid = threadIdx.x;
  const int bm = blockIdx.x, bn = blockIdx.y, z = blockIdx.z;
  const int wsel = (EPI == EPI_TOK) ? sidx[z] : z;
  const int lane = tid & 63, wave = tid >> 6;
  const int wm = (wave & 1) << 6, wn = (wave >> 1) << 6;
  const int r16 = lane & 15, quad = lane >> 4;

  __shared__ bf16 sA[128 * SLDA];
  __shared__ bf16 sB[128 * SLDA];

  const bf16* Ag = A + (long)z * zA + (long)bm * 128 * K;
  const bf16* Wg = W + (long)wsel * zW + (long)bn * 128 * K;

  f32x4 zf = {0.f, 0.f, 0.f, 0.f};
  f32x4 acc[4][4];
  for (int i = 0; i < 4; ++i) for (int j = 0; j < 4; ++j) acc[i][j] = zf;

  const int sr = tid >> 1, sc = (tid & 1) << 4;
  for (int k0 = 0; k0 < K; k0 += 32) {
    *(short8*)&sA[sr*SLDA + sc]     = *(const short8*)&Ag[(long)sr*K + k0 + sc];
    *(short8*)&sA[sr*SLDA + sc + 8] = *(const short8*)&Ag[(long)sr*K + k0 + sc + 8];
    *(short8*)&sB[sr*SLDA + sc]     = *(const short8*)&Wg[(long)sr*K + k0 + sc];
    *(short8*)&sB[sr*SLDA + sc + 8] = *(const short8*)&Wg[(long)sr*K + k0 + sc + 8];
    __syncthreads();
    short8 fa[4], fb[4];
    for (int i = 0; i < 4; ++i) fa[i] = *(const short8*)&sA[(wm + i*16 + r16)*SLDA + quad*8];
    for (int j = 0; j < 4; ++j) fb[j] = *(const short8*)&sB[(wn + j*16 + r16)*SLDA + quad*8];
    for (int i = 0; i < 4; ++i)
      for (int j = 0; j < 4; ++j)
        acc[i][j] = __builtin_amdgcn_mfma_f32_16x16x32_bf16(fa[i], fb[j], acc[i][j], 0, 0, 0);
    __syncthreads();
  }

  const float* bz = bias + (long)wsel * zB + bn * 128;
  for (int i = 0; i < 4; ++i) {
    for (int j = 0; j < 4; ++j) {
      const int colL = wn + j*16 + r16;
      const float bv = bz[colL];
      for (int r = 0; r < 4; ++r) {
        float v = acc[i][j][r] + bv;
        const long grow = (long)bm*128 + wm + i*16 + quad*4 + r;
        const long gcol = (long)bn*128 + colL;
        if (EPI == EPI_F32) {
          ((float*)C)[(long)z*zC + grow*ldc + gcol] = v;
        } else if (EPI == EPI_BF16) {
          ((bf16*)C)[(long)z*zC + grow*ldc + gcol] = __float2bfloat16(v);
        } else if (EPI == EPI_GELU) {
          v = 0.5f * v * (1.0f + erff(v * 0.70710678118654752f));
          ((bf16*)C)[(long)z*zC + grow*ldc + gcol] = __float2bfloat16(v);
        } else if (EPI == EPI_F32R) {
          // rows are [n*64+b]; output wants [b*510+n]
          const long rb = grow & 63, rn = grow >> 6;
          ((float*)C)[(rb*510 + rn)*ldc + gcol] = v;
        } else { // EPI_TOK: z=batch, grow=t, gcol=e
          for (int p = 0; p < 3; ++p) {
            long n = grow - p;
            if (n >= 0 && n < N_) {
              tokf[((long)z*N_ + n)*TOK_ + gcol*3 + p] = v;                 // d_out: [b][n][tok]
              tokb[((long)n*B_ + z)*TOK_ + gcol*3 + p] = __float2bfloat16(v); // ws: rows [n*64+b]
            }
          }
        }
      }
    }
  }
}

// ---------------- RMSNorm rows of 512: fp32 in -> bf16 out ----------------
__global__ __launch_bounds__(256) void k_rms(const float* __restrict__ hpre,
                                             const float* __restrict__ scale,
                                             bf16* __restrict__ hbf)
{
  const int wave = threadIdx.x >> 6, lane = threadIdx.x & 63;
  const long row = (long)blockIdx.x * 4 + wave;
  const float* p = hpre + row * 512 + lane * 8;
  float4 v0 = *(const float4*)p;
  float4 v1 = *(const float4*)(p + 4);
  float ss = v0.x*v0.x + v0.y*v0.y + v0.z*v0.z + v0.w*v0.w
           + v1.x*v1.x + v1.y*v1.y + v1.z*v1.z + v1.w*v1.w;
  for (int m = 32; m >= 1; m >>= 1) ss += __shfl_xor(ss, m, 64);
  const float inv = 1.0f / sqrtf(ss * (1.0f/512.0f) + 1e-6f);
  const float* sc = scale + lane * 8;
  union { short8 sv; bf16 h[8]; } u;
  u.h[0] = __float2bfloat16(v0.x*inv*sc[0]); u.h[1] = __float2bfloat16(v0.y*inv*sc[1]);
  u.h[2] = __float2bfloat16(v0.z*inv*sc[2]); u.h[3] = __float2bfloat16(v0.w*inv*sc[3]);
  u.h[4] = __float2bfloat16(v1.x*inv*sc[4]); u.h[5] = __float2bfloat16(v1.y*inv*sc[5]);
  u.h[6] = __float2bfloat16(v1.z*inv*sc[6]); u.h[7] = __float2bfloat16(v1.w*inv*sc[7]);
  *(short8*)(hbf + row * 512 + lane * 8) = u.sv;
}

// ---------------- GRU: flagless self-certifying persistent scan ----------------
// 8 independent batch-groups of 8 batches; per group 32 single-wave WGs
// (grid 256 x 64 thr, 1 wave/CU). Wave pw owns cols [16pw,16pw+16), all 3 gates.
// SYNC REDESIGN (r6 lesson: flag protocol = ~1700cy/step of L3 round trips):
//   |h| < 1 strictly, so a stored dword (2 packed bf16) can never be 0xFFFFFFFF.
//   hidden[] is pre-memset to 0xFF. Producers just store (no ack, no flag).
//   Consumers speculatively DMA h[s-1], load A-frags (needed anyway), and
//   validate by v_max_u32-accumulating their 64 dwords: any 0xFFFFFFFF ->
//   re-DMA. Dword stores are atomic, so any store order is safe; every dword
//   consumed is individually checked (full coverage: lane (quad,c16) checks
//   row c16&7, cols kt*32+quad*8..+8 over kt -> union = all 8 rows x 512 cols).
//   No deadlock: the group-minimum-step wave always has all deps written.
#define KP 520   // LDS row pad (elems)

// aux=16 == CPol SC1 on gfx950: device-scope load (coherent past L2)
#define GL2LDS(g, l) __builtin_amdgcn_global_load_lds( \
    (const __attribute__((address_space(1))) void*)(g), \
    (__attribute__((address_space(3))) void*)(l), 16, 0, 16)

__global__ __launch_bounds__(64, 1) void k_gru(
    const bf16* __restrict__ gx,   // [s][b][1536] bf16 (bih already added)
    const bf16* __restrict__ Whh,  // [1536][512] bf16
    const float* __restrict__ bhh, // [1536]
    bf16* __restrict__ hidden)     // [s][b][512] bf16, pre-memset 0xFF
{
  const int lane = threadIdx.x & 63;
  const int c16  = lane & 15, quad = lane >> 4;
  const int pw   = blockIdx.x & 31;     // producer-wave id within group
  const int gb   = blockIdx.x >> 5;     // batch group
  const int hwv  = pw * 16;             // column base
  const int b0   = gb * 8;              // batch base

  __shared__ bf16 wlds[16 * 3 * 64 * 8];  // [kt][gate][lane*8] : 49,152 B
  __shared__ bf16 hp[8 * KP];             // h_prev rows (DMA dest): 8,320 B

  // one-time stage: B-frag for (kt,gate) at this lane = Whh row (g*512+hwv+c16),
  // cols kt*32+quad*8 .. +8  -> stored lane-contiguous (conflict-free)
  for (int g3 = 0; g3 < 3; ++g3)
    for (int kt = 0; kt < 16; ++kt)
      *(short8*)&wlds[((kt*3 + g3)*64 + lane)*8] =
          *(const short8*)&Whh[(long)(g3*512 + hwv + c16)*512 + kt*32 + quad*8];
  const float bhr = bhh[       hwv + c16];
  const float bhz = bhh[ 512 + hwv + c16];
  const float bhn = bhh[1024 + hwv + c16];
  __syncthreads();

  // lane owns output batch rows brv..brv+3 (valid for quad<2; quads 2,3 mirror)
  const int brv = (quad & 1) * 4;

  float gr[4], gz[4], gn[4];
  float hcur[4] = {0.f, 0.f, 0.f, 0.f};   // own cols' h (z*h_prev term), in regs
  { // gx for s=0
    const bf16* gxs = gx + (long)b0 * 1536 + hwv + c16;
#pragma unroll
    for (int i2 = 0; i2 < 4; ++i2) {
      const long ro = (long)(brv + i2) * 1536;
      gr[i2] = __bfloat162float(gxs[ro]);
      gz[i2] = __bfloat162float(gxs[ro + 512]);
      gn[i2] = __bfloat162float(gxs[ro + 1024]);
    }
  }

  for (int s = 0; s < 510; ++s) {
    f32x4 ar = {0.f,0.f,0.f,0.f}, az = {0.f,0.f,0.f,0.f}, an = {0.f,0.f,0.f,0.f};

    if (s > 0) {
      // speculative DMA + validate-retry: the DMA IS the poll.
      union AU { unsigned u[4]; short8 s8; } au[16];
      const bf16* src = hidden + ((long)(s-1)*64 + b0)*512 + lane*8;
      while (true) {
#pragma unroll
        for (int b = 0; b < 8; ++b) GL2LDS(src + b*512, &hp[b*KP]);
        asm volatile("s_waitcnt vmcnt(0)" ::: "memory");  // DMA landed in hp
        // A-frag loads double as validation reads
        unsigned mx = 0u;
#pragma unroll
        for (int kt = 0; kt < 16; ++kt) {
          au[kt].s8 = *(const short8*)&hp[(c16 & 7)*KP + kt*32 + quad*8];
          unsigned m01 = au[kt].u[0] > au[kt].u[1] ? au[kt].u[0] : au[kt].u[1];
          unsigned m23 = au[kt].u[2] > au[kt].u[3] ? au[kt].u[2] : au[kt].u[3];
          unsigned m = m01 > m23 ? m01 : m23;
          mx = mx > m ? mx : m;
        }
        // legit dwords are two bf16 of |h|<1 -> each half <= 0xBF7F -> never all-ones
        if (__all(mx != 0xFFFFFFFFu)) break;
      }

      // 48 MFMAs, 3 independent chains; A-frags already in regs, B from wlds
#pragma unroll
      for (int kt = 0; kt < 16; ++kt) {
        short8 fr = *(const short8*)&wlds[((kt*3 + 0)*64 + lane)*8];
        short8 fz = *(const short8*)&wlds[((kt*3 + 1)*64 + lane)*8];
        short8 fn = *(const short8*)&wlds[((kt*3 + 2)*64 + lane)*8];
        ar = __builtin_amdgcn_mfma_f32_16x16x32_bf16(au[kt].s8, fr, ar, 0, 0, 0);
        az = __builtin_amdgcn_mfma_f32_16x16x32_bf16(au[kt].s8, fz, az, 0, 0, 0);
        an = __builtin_amdgcn_mfma_f32_16x16x32_bf16(au[kt].s8, fn, an, 0, 0, 0);
      }
    }

    // gates + publish (only quad<2 lanes own valid batch rows)
    if (quad < 2) {
#pragma unroll
      for (int i2 = 0; i2 < 4; ++i2) {
        const float r  = 1.0f / (1.0f + expf(-(gr[i2] + ar[i2] + bhr)));
        const float z  = 1.0f / (1.0f + expf(-(gz[i2] + az[i2] + bhz)));
        const float nn = tanhf(gn[i2] + r * (an[i2] + bhn));
        const float hn = (1.0f - z)*nn + z*hcur[i2];
        union { bf16 h; unsigned short u; } cb; cb.h = __float2bfloat16(hn);
        hcur[i2] = __bfloat162float(cb.h);     // exact stored value for next step
        unsigned mine = cb.u;
        unsigned part = (unsigned)__shfl_xor((int)mine, 1, 64);
        if (!(c16 & 1)) {
          unsigned w = (part << 16) | mine;    // lo = col c16, hi = col c16+1
          // device-scope write-through store; dword atomicity = validity granule.
          // No ack, no flag: consumers self-validate against the 0xFF sentinel.
          __hip_atomic_store((unsigned*)(hidden + ((long)s*64 + b0 + brv + i2)*512 + hwv + c16),
                             w, __ATOMIC_RELAXED, __HIP_MEMORY_SCOPE_AGENT);
        }
      }
    }
    if (s < 509) {
      asm volatile("" ::: "memory");  // keep gx prefetch BELOW the stores
      // prefetch gx for s+1 -- latency hides under next step's DMA/validate
      const bf16* gxs = gx + ((long)(s+1)*64 + b0)*1536 + hwv + c16;
#pragma unroll
      for (int i2 = 0; i2 < 4; ++i2) {
        const long ro = (long)(brv + i2) * 1536;
        gr[i2] = __bfloat162float(gxs[ro]);
        gz[i2] = __bfloat162float(gxs[ro + 512]);
        gn[i2] = __bfloat162float(gxs[ro + 1024]);
      }
    }
  }
}

// ---------------- launch ----------------
extern "C" void kernel_launch(void* const* d_in, const int* in_sizes, int n_in,
                              void* d_out, int out_size, void* d_ws, size_t ws_size,
                              hipStream_t stream)
{
  const float* x    = (const float*)d_in[0];
  const int*   sidx = (const int*)d_in[1];
  const float* sW   = (const float*)d_in[2];
  const float* sb   = (const float*)d_in[3];
  const float* pW   = (const float*)d_in[4];
  const float* pb   = (const float*)d_in[5];
  const float* rsc  = (const float*)d_in[6];
  const float* wih  = (const float*)d_in[7];
  const float* whh  = (const float*)d_in[8];
  const float* bih  = (const float*)d_in[9];
  const float* bhh  = (const float*)d_in[10];
  const float* w1   = (const float*)d_in[11];
  const float* b1   = (const float*)d_in[12];
  const float* w2   = (const float*)d_in[13];
  const float* b2   = (const float*)d_in[14];
  char* ws = (char*)d_ws;
  float* out = (float*)d_out;

  bf16* xbf   = (bf16*)(ws + O_XBF);
  bf16* swbf  = (bf16*)(ws + O_SWB);
  bf16* pwbf  = (bf16*)(ws + O_PW);
  bf16* wihbf = (bf16*)(ws + O_WIH);
  bf16* whhbf = (bf16*)(ws + O_WHH);
  bf16* w1bf  = (bf16*)(ws + O_W1);
  bf16* w2bf  = (bf16*)(ws + O_W2);
  bf16* tokbf = (bf16*)(ws + O_TOK);
  bf16* hbf   = (bf16*)(ws + O_HBF);
  bf16* hidbf = (bf16*)(ws + O_HID);
  bf16* abf   = (bf16*)(ws + O_ABF);
  float* hpre = (float*)(ws + O_GX);  // fp32 h_pre overlaps gx region
  bf16* gxbf  = (bf16*)(ws + O_GX);

  // sentinel-fill hidden: 0xFF bytes = bf16 -NaN dwords, never produced by the GRU
  hipMemsetAsync(ws + O_HID, 0xFF, HID_BYTES, stream);

  auto cvt = [&](const float* s, bf16* dp, long n) {
    int n4 = (int)(n >> 2);
    k_f2b<<<dim3((n4 + 255) / 256), dim3(256), 0, stream>>>(s, dp, n4);
  };
  cvt(x,   xbf,   (long)B_*T_*D_);
  cvt(sW,  swbf,  16L*128*128);
  cvt(pW,  pwbf,  512L*384);
  cvt(wih, wihbf, 1536L*512);
  cvt(whh, whhbf, 1536L*512);
  cvt(w1,  w1bf,  3L*512*512);
  cvt(w2,  w2bf,  3L*384*512);

  // 1) session align -> tokens (fp32 to d_out [b][n][tok], bf16 to ws rows [n*64+b])
  k_gemm<EPI_TOK><<<dim3(4, 1, 64), dim3(256), 0, stream>>>(
      xbf, swbf, sb, nullptr, 128, 0,
      (long)T_*D_, 128L*128, 128L, 0L, sidx, out + TOKOFF_, tokbf);

  // 2) proj: h_pre = tokens @ proj_W^T + b  (fp32, rows [n*64+b])
  k_gemm<EPI_F32><<<dim3(255, 4, 1), dim3(256), 0, stream>>>(
      tokbf, pwbf, pb, hpre, 384, 512, 0, 0, 0, 0, nullptr, nullptr, nullptr);

  // 3) RMSNorm -> h bf16
  k_rms<<<dim3(8160), dim3(256), 0, stream>>>(hpre, rsc, hbf);

  // 4) gx = h @ Wih^T + bih  (bf16, rows [n*64+b] == [s][b][1536])
  k_gemm<EPI_BF16><<<dim3(255, 12, 1), dim3(256), 0, stream>>>(
      hbf, wihbf, bih, gxbf, 512, 1536, 0, 0, 0, 0, nullptr, nullptr, nullptr);

  // 5) GRU scan: 8 groups x 32 single-wave WGs = 256 WGs x 64 thr (1 wave/CU).
  //    Flagless: correctness carried by the 0xFF sentinel pre-fill above.
  k_gru<<<dim3(256), dim3(64), 0, stream>>>(gxbf, whhbf, bhh, hidbf);

  // 6) heads: a = gelu(hidden @ W1^T + b1); preds = a @ W2^T + b2 (remap rows)
  for (int k = 0; k < 3; ++k) {
    k_gemm<EPI_GELU><<<dim3(255, 4, 1), dim3(256), 0, stream>>>(
        hidbf, w1bf + (long)k*512*512, b1 + (long)k*512, abf,
        512, 512, 0, 0, 0, 0, nullptr, nullptr, nullptr);
    k_gemm<EPI_F32R><<<dim3(255, 3, 1), dim3(256), 0, stream>>>(
        abf, w2bf + (long)k*384*512, b2 + (long)k*384, out + (long)k*PRED1_,
        512, 384, 0, 0, 0, 0, nullptr, nullptr, nullptr);
  }
}